// Round 5
// baseline (96.280 us; speedup 1.0000x reference)
//
#include <hip/hip_runtime.h>
#include <math.h>

#define BDIM 256

constexpr int Vc = 20000, Cc = 32, NBc = 12, KSc = 9, OUTc = 32;
constexpr int NTASK = 40000;
constexpr int UXP   = 12;              // padded ux row (float4-aligned)
constexpr int MT    = 16;              // tasks per wave-iteration (MFMA M)
constexpr int NITER = NTASK / MT;      // 2500 exact
constexpr int NBLK  = 512;             // persistent: 2 blocks/CU
constexpr int NWAVE = NBLK * 4;        // 2048 wave slots
constexpr int WFE   = KSc * 2 * 64 * 8;  // 9216 frag elems (hi); lo follows

typedef __attribute__((ext_vector_type(8))) short short8;    // 8 bf16 = 4 VGPRs
typedef __attribute__((ext_vector_type(4))) float floatx4;   // MFMA C/D

// ---------- kernel 1: ux precompute (blocks 0..156) + W frag build (blocks 157..192) ----------
__global__ __launch_bounds__(BDIM)
void prep_kernel(const float* __restrict__ x, const float* __restrict__ u,
                 const float* __restrict__ W, float* __restrict__ ux,
                 unsigned short* __restrict__ wf)
{
    if (blockIdx.x < 157) {
        // ---- ux[row,k] = sum_c x[row,c] * u[c,k] ----
        __shared__ float us[Cc * KSc];
        for (int i = threadIdx.x; i < Cc * KSc; i += BDIM) us[i] = u[i];
        __syncthreads();
        const int row = blockIdx.x * BDIM + threadIdx.x;
        if (row >= NTASK) return;
        const float4* xr = (const float4*)(x + row * Cc);
        float4 xv[8];
#pragma unroll
        for (int i = 0; i < 8; ++i) xv[i] = xr[i];
        float acc[KSc];
#pragma unroll
        for (int k = 0; k < KSc; ++k) acc[k] = 0.f;
#pragma unroll
        for (int c = 0; c < Cc; ++c) {
            const float xc = ((const float*)xv)[c];
#pragma unroll
            for (int k = 0; k < KSc; ++k) acc[k] = fmaf(xc, us[c * KSc + k], acc[k]);
        }
        float4* o4 = (float4*)(ux + row * UXP);
        o4[0] = make_float4(acc[0], acc[1], acc[2], acc[3]);
        o4[1] = make_float4(acc[4], acc[5], acc[6], acc[7]);
        o4[2] = make_float4(acc[8], 0.f, 0.f, 0.f);
    } else {
        // ---- W bf16 hi/lo MFMA B-fragments, B[c][o] layout for 16x16x32 ----
        const int e = (blockIdx.x - 157) * BDIM + threadIdx.x;   // [0, 9216)
        if (e >= WFE) return;
        const int j = e & 7;
        const int l = (e >> 3) & 63;
        const int h = (e >> 9) & 1;
        const int k = e >> 10;                  // 0..8
        const int c = (l >> 4) * 8 + j;         // B k-dim elem = channel
        const int o = (l & 15) + 16 * h;        // B n-dim = output col
        const float w = W[(c * KSc + k) * OUTc + o];
        const unsigned int bits = __float_as_uint(w);
        const unsigned short hi = (unsigned short)(bits >> 16);   // truncate -> lo captures rest
        const float hif = __uint_as_float(bits & 0xFFFF0000u);
        const float lof = w - hif;
        const unsigned short lo = (unsigned short)(__float_as_uint(lof) >> 16);
        wf[e]       = hi;
        wf[WFE + e] = lo;
    }
}

// ---------- kernel 2: fused softmax-aggregate + MFMA projection ----------
__global__ __launch_bounds__(BDIM, 2)
void fused_kernel(const float* __restrict__ x, const float* __restrict__ cvec,
                  const float* __restrict__ bvec, const int* __restrict__ adj,
                  const float* __restrict__ ux, const unsigned short* __restrict__ wf,
                  float* __restrict__ out)
{
    __shared__ __align__(16) unsigned short wsh[2 * WFE];     // 36864 B: hi frags, then lo
    __shared__ __align__(16) float qs[4][MT][KSc][NBc];       // 27648 B (t-stride 108 dw -> 2-way max)
    __shared__ __align__(16) int   js[4][MT][NBc];            //  3072 B
    __shared__ float invs[4][MT];                             //   256 B

    const int tid = threadIdx.x;
    // stage W frags global->LDS, coalesced uint4
    {
        const uint4* src = (const uint4*)wf;
        uint4* dst = (uint4*)wsh;
        for (int i = tid; i < (2 * WFE) / 8; i += BDIM) dst[i] = src[i];
    }
    float ck[KSc];
#pragma unroll
    for (int k = 0; k < KSc; ++k) ck[k] = cvec[k];
    const int l64 = tid & 63;
    const int w   = tid >> 6;
    const int oo  = l64 & 15;     // MFMA n / D col
    const int cb  = l64 >> 4;     // c-block for A, row-quad for D
    const float b0 = bvec[oo], b1 = bvec[oo + 16];
    __syncthreads();              // only barrier; waves loop independently

    const int gw = blockIdx.x * 4 + w;
    for (int it = gw; it < NITER; it += NWAVE) {
        const int t0 = it * MT;

        // ---- softmax: 3 passes x 64 lanes cover 16 tasks x 12 neighbors ----
#pragma unroll
        for (int p = 0; p < 3; ++p) {
            const int unit = p * 64 + l64;                 // [0,192)
            const int t    = (unit * 171) >> 11;           // floor(unit/12), exact for unit<192
            const int n    = unit - t * 12;
            const int task = t0 + t;
            const int bb   = (task >= Vc) ? 1 : 0;
            const int v    = task - bb * Vc;
            const int jn   = adj[v * NBc + n];
            const bool pred = (jn != 0);
            const int row = pred ? (bb * Vc + jn - 1) : 0;
            js[w][t][n] = row;
            float uo[12], un[12];
            {
                const float4* uo4 = (const float4*)(ux + task * UXP);
                const float4* un4 = (const float4*)(ux + row * UXP);
                *(float4*)&uo[0] = uo4[0]; *(float4*)&uo[4] = uo4[1]; *(float4*)&uo[8] = uo4[2];
                *(float4*)&un[0] = un4[0]; *(float4*)&un[4] = un4[1]; *(float4*)&un[8] = un4[2];
            }
            float e[KSc];
            float mx = -3.0e38f;
#pragma unroll
            for (int k = 0; k < KSc; ++k) {
                e[k] = uo[k] - un[k] + ck[k];
                mx = fmaxf(mx, e[k]);
            }
            float s = 0.f;
#pragma unroll
            for (int k = 0; k < KSc; ++k) { e[k] = __expf(e[k] - mx); s += e[k]; }
            const float r = pred ? (1.f / s) : 0.f;        // q=0 for padded neighbors
#pragma unroll
            for (int k = 0; k < KSc; ++k) qs[w][t][k][n] = e[k] * r;
        }
        // ---- inv_deg per task (lanes 0..15) ----
        if (l64 < MT) {
            const int task = t0 + l64;
            const int bb   = (task >= Vc) ? 1 : 0;
            const int v    = task - bb * Vc;
            const int4* ar = (const int4*)(adj + v * NBc);
            const int4 a0 = ar[0], a1 = ar[1], a2 = ar[2];
            const int d = (a0.x != 0) + (a0.y != 0) + (a0.z != 0) + (a0.w != 0)
                        + (a1.x != 0) + (a1.y != 0) + (a1.z != 0) + (a1.w != 0)
                        + (a2.x != 0) + (a2.y != 0) + (a2.z != 0) + (a2.w != 0);
            invs[w][l64] = (d > 0) ? 1.f / (float)d : 0.f;
        }
        // same-wave LDS write->read below: DS ops issue in order, no barrier needed

        // ---- y phase, directly in MFMA A-layout: lane = (task oo? no: t = oo? ) ----
        // lane l64: A row m = l64&15 (task t0+oo ... careful: m = l64&15), k-elems c = cb*8+j
        const int tA = l64 & 15;   // this lane's task (A row)
        float y[KSc][8];
#pragma unroll
        for (int k = 0; k < KSc; ++k)
#pragma unroll
            for (int j = 0; j < 8; ++j) y[k][j] = 0.f;

        int rows[NBc];
        {
            const int4* jp = (const int4*)&js[w][tA][0];
            const int4 ja = jp[0], jb = jp[1], jc = jp[2];
            rows[0] = ja.x; rows[1] = ja.y; rows[2]  = ja.z; rows[3]  = ja.w;
            rows[4] = jb.x; rows[5] = jb.y; rows[6]  = jb.z; rows[7]  = jb.w;
            rows[8] = jc.x; rows[9] = jc.y; rows[10] = jc.z; rows[11] = jc.w;
        }
#pragma unroll
        for (int nb = 0; nb < 3; ++nb) {
            float xs[4][8];
#pragma unroll
            for (int i = 0; i < 4; ++i) {
                const float4* xp = (const float4*)(x + rows[nb * 4 + i] * Cc + cb * 8);
                *(float4*)&xs[i][0] = xp[0];
                *(float4*)&xs[i][4] = xp[1];
            }
#pragma unroll
            for (int k = 0; k < KSc; ++k) {
                const float4 q4 = *(const float4*)&qs[w][tA][k][nb * 4];
#pragma unroll
                for (int j = 0; j < 8; ++j) {
                    float a = y[k][j];
                    a = fmaf(q4.x, xs[0][j], a);
                    a = fmaf(q4.y, xs[1][j], a);
                    a = fmaf(q4.z, xs[2][j], a);
                    a = fmaf(q4.w, xs[3][j], a);
                    y[k][j] = a;
                }
            }
        }

        // ---- MFMA projection: res[16x32] = y[16x288] . W[288x32], hi/lo split ----
        floatx4 acc0 = {0.f, 0.f, 0.f, 0.f};
        floatx4 acc1 = {0.f, 0.f, 0.f, 0.f};
#pragma unroll
        for (int k = 0; k < KSc; ++k) {
            short8 ah, al;
#pragma unroll
            for (int j = 0; j < 8; ++j) {
                const unsigned int yb = __float_as_uint(y[k][j]);
                ah[j] = (short)(yb >> 16);
                const float hif = __uint_as_float(yb & 0xFFFF0000u);
                const float lof = y[k][j] - hif;
                al[j] = (short)(__float_as_uint(lof) >> 16);
            }
            const short8 bh0 = *(const short8*)&wsh[((k * 2 + 0) * 64 + l64) * 8];
            const short8 bh1 = *(const short8*)&wsh[((k * 2 + 1) * 64 + l64) * 8];
            const short8 bl0 = *(const short8*)&wsh[WFE + ((k * 2 + 0) * 64 + l64) * 8];
            const short8 bl1 = *(const short8*)&wsh[WFE + ((k * 2 + 1) * 64 + l64) * 8];
            acc0 = __builtin_amdgcn_mfma_f32_16x16x32_bf16(ah, bh0, acc0, 0, 0, 0);
            acc0 = __builtin_amdgcn_mfma_f32_16x16x32_bf16(al, bh0, acc0, 0, 0, 0);
            acc0 = __builtin_amdgcn_mfma_f32_16x16x32_bf16(ah, bl0, acc0, 0, 0, 0);
            acc1 = __builtin_amdgcn_mfma_f32_16x16x32_bf16(ah, bh1, acc1, 0, 0, 0);
            acc1 = __builtin_amdgcn_mfma_f32_16x16x32_bf16(al, bh1, acc1, 0, 0, 0);
            acc1 = __builtin_amdgcn_mfma_f32_16x16x32_bf16(ah, bl1, acc1, 0, 0, 0);
        }

        // ---- epilogue: D row = cb*4 + r (task), col = oo; scale+bias+relu, store ----
#pragma unroll
        for (int r = 0; r < 4; ++r) {
            const int tl   = cb * 4 + r;
            const float nv = invs[w][tl];
            const int task = t0 + tl;
            out[task * OUTc + oo]      = fmaxf(fmaf(acc0[r], nv, b0), 0.f);
            out[task * OUTc + oo + 16] = fmaxf(fmaf(acc1[r], nv, b1), 0.f);
        }
    }
}

extern "C" void kernel_launch(void* const* d_in, const int* in_sizes, int n_in,
                              void* d_out, int out_size, void* d_ws, size_t ws_size,
                              hipStream_t stream)
{
    const float* x    = (const float*)d_in[0];
    const float* W    = (const float*)d_in[1];
    const float* u    = (const float*)d_in[2];
    const float* cvec = (const float*)d_in[3];
    const float* bvec = (const float*)d_in[4];
    const int*   adj  = (const int*)d_in[5];
    float* out = (float*)d_out;

    float*          ux = (float*)d_ws;                                  // 1,920,000 B
    unsigned short* wf = (unsigned short*)((char*)d_ws + 1920000);      // 36,864 B

    prep_kernel<<<157 + 36, BDIM, 0, stream>>>(x, u, W, ux, wf);
    fused_kernel<<<NBLK, BDIM, 0, stream>>>(x, cvec, bvec, adj, ux, wf, out);
}

// Round 6
// 88.066 us; speedup vs baseline: 1.0933x; 1.0933x over previous
//
#include <hip/hip_runtime.h>
#include <math.h>

#define PBDIM 256   // prep kernel block
#define BDIM  64    // fused kernel: ONE wave per block

constexpr int Vc = 20000, Cc = 32, NBc = 12, KSc = 9, OUTc = 32;
constexpr int NTASK = 40000;
constexpr int UXP   = 12;              // padded ux row (float4-aligned)
constexpr int MT    = 16;              // tasks per wave (MFMA M)
constexpr int NITER = NTASK / MT;      // 2500 exact = grid size
constexpr int WFE   = KSc * 2 * 64 * 8;  // 9216 frag elems (hi); lo follows

typedef __attribute__((ext_vector_type(8))) short short8;    // 8 bf16 = 4 VGPRs
typedef __attribute__((ext_vector_type(4))) float floatx4;   // MFMA C/D

// ---------- kernel 1: ux precompute (blocks 0..156) + W frag build (blocks 157..192) ----------
__global__ __launch_bounds__(PBDIM)
void prep_kernel(const float* __restrict__ x, const float* __restrict__ u,
                 const float* __restrict__ W, float* __restrict__ ux,
                 unsigned short* __restrict__ wf)
{
    if (blockIdx.x < 157) {
        __shared__ float us[Cc * KSc];
        for (int i = threadIdx.x; i < Cc * KSc; i += PBDIM) us[i] = u[i];
        __syncthreads();
        const int row = blockIdx.x * PBDIM + threadIdx.x;
        if (row >= NTASK) return;
        const float4* xr = (const float4*)(x + row * Cc);
        float4 xv[8];
#pragma unroll
        for (int i = 0; i < 8; ++i) xv[i] = xr[i];
        float acc[KSc];
#pragma unroll
        for (int k = 0; k < KSc; ++k) acc[k] = 0.f;
#pragma unroll
        for (int c = 0; c < Cc; ++c) {
            const float xc = ((const float*)xv)[c];
#pragma unroll
            for (int k = 0; k < KSc; ++k) acc[k] = fmaf(xc, us[c * KSc + k], acc[k]);
        }
        float4* o4 = (float4*)(ux + row * UXP);
        o4[0] = make_float4(acc[0], acc[1], acc[2], acc[3]);
        o4[1] = make_float4(acc[4], acc[5], acc[6], acc[7]);
        o4[2] = make_float4(acc[8], 0.f, 0.f, 0.f);
    } else {
        // W bf16 hi/lo MFMA B-fragments, B[c][o] layout for 16x16x32 (identical to round 5)
        const int e = (blockIdx.x - 157) * PBDIM + threadIdx.x;   // [0, 9216)
        if (e >= WFE) return;
        const int j = e & 7;
        const int l = (e >> 3) & 63;
        const int h = (e >> 9) & 1;
        const int k = e >> 10;                  // 0..8
        const int c = (l >> 4) * 8 + j;         // B k-dim elem = channel
        const int o = (l & 15) + 16 * h;        // B n-dim = output col
        const float w = W[(c * KSc + k) * OUTc + o];
        const unsigned int bits = __float_as_uint(w);
        const unsigned short hi = (unsigned short)(bits >> 16);   // truncate -> lo captures rest
        const float hif = __uint_as_float(bits & 0xFFFF0000u);
        const float lof = w - hif;
        const unsigned short lo = (unsigned short)(__float_as_uint(lof) >> 16);
        wf[e]       = hi;
        wf[WFE + e] = lo;
    }
}

// ---------- kernel 2: one wave = 16 tasks; softmax+aggregate+MFMA, no barriers ----------
__global__ __launch_bounds__(BDIM, 3)
void fused_kernel(const float* __restrict__ x, const float* __restrict__ cvec,
                  const float* __restrict__ bvec, const int* __restrict__ adj,
                  const float* __restrict__ ux, const unsigned short* __restrict__ wf,
                  float* __restrict__ out)
{
    __shared__ __align__(16) float qs[MT][KSc][NBc];   // 6912 B, only LDS use

    const int l64 = threadIdx.x;
    const int oo  = l64 & 15;     // MFMA n / D col
    const int cb  = l64 >> 4;     // c-block for A, row-quad for D
    const int t0  = blockIdx.x * MT;

    float ck[KSc];
#pragma unroll
    for (int k = 0; k < KSc; ++k) ck[k] = cvec[k];

    // ---- softmax: 3 passes x 64 lanes = 16 tasks x 12 neighbors; loads hoisted ----
    int   tP[3], nP[3], rowP[3];
    bool  predP[3];
    float uo[3][12], un[3][12];
#pragma unroll
    for (int p = 0; p < 3; ++p) {
        const int unit = p * 64 + l64;              // [0,192)
        const int t    = (unit * 171) >> 11;        // floor(unit/12), exact for unit<192
        const int n    = unit - t * 12;
        const int task = t0 + t;
        const int bb   = (task >= Vc) ? 1 : 0;
        const int v    = task - bb * Vc;
        const int jn   = adj[v * NBc + n];          // coalesced (contiguous units)
        predP[p] = (jn != 0);
        rowP[p]  = predP[p] ? (bb * Vc + jn - 1) : 0;
        tP[p] = t; nP[p] = n;
    }
#pragma unroll
    for (int p = 0; p < 3; ++p) {                   // all 18 gather loads in flight together
        const float4* uo4 = (const float4*)(ux + (t0 + tP[p]) * UXP);
        const float4* un4 = (const float4*)(ux + rowP[p] * UXP);
        *(float4*)&uo[p][0] = uo4[0]; *(float4*)&uo[p][4] = uo4[1]; *(float4*)&uo[p][8] = uo4[2];
        *(float4*)&un[p][0] = un4[0]; *(float4*)&un[p][4] = un4[1]; *(float4*)&un[p][8] = un4[2];
    }
#pragma unroll
    for (int p = 0; p < 3; ++p) {
        float e[KSc];
        float mx = -3.0e38f;
#pragma unroll
        for (int k = 0; k < KSc; ++k) {
            e[k] = uo[p][k] - un[p][k] + ck[k];
            mx = fmaxf(mx, e[k]);
        }
        float s = 0.f;
#pragma unroll
        for (int k = 0; k < KSc; ++k) { e[k] = __expf(e[k] - mx); s += e[k]; }
        const float r = predP[p] ? (1.f / s) : 0.f;   // q=0 for padded neighbors
#pragma unroll
        for (int k = 0; k < KSc; ++k) qs[tP[p]][k][nP[p]] = e[k] * r;
    }
    // same-wave LDS write->read below: DS ops issue in order, no barrier needed

    // ---- per-lane task metadata from adj directly (no LDS js/invs) ----
    const int tA   = l64 & 15;                     // this lane's task (A row)
    const int task = t0 + tA;
    const int bb   = (task >= Vc) ? 1 : 0;
    const int v    = task - bb * Vc;
    int rows[NBc];
    float inv_local;
    {
        const int4* ar = (const int4*)(adj + v * NBc);   // 768 B/wave, L1-broadcast
        const int4 a0 = ar[0], a1 = ar[1], a2 = ar[2];
        int jv[NBc];
        jv[0] = a0.x; jv[1] = a0.y; jv[2]  = a0.z; jv[3]  = a0.w;
        jv[4] = a1.x; jv[5] = a1.y; jv[6]  = a1.z; jv[7]  = a1.w;
        jv[8] = a2.x; jv[9] = a2.y; jv[10] = a2.z; jv[11] = a2.w;
        int d = 0;
#pragma unroll
        for (int n = 0; n < NBc; ++n) {
            const bool pr = (jv[n] != 0);
            d += pr ? 1 : 0;
            rows[n] = pr ? (bb * Vc + jv[n] - 1) : 0;
        }
        inv_local = (d > 0) ? 1.f / (float)d : 0.f;
    }

    // ---- y phase in MFMA A-layout: lane holds y[k][j] for c = cb*8+j ----
    float y[KSc][8];
#pragma unroll
    for (int k = 0; k < KSc; ++k)
#pragma unroll
        for (int j = 0; j < 8; ++j) y[k][j] = 0.f;

#pragma unroll
    for (int nb = 0; nb < 3; ++nb) {
        float xs[4][8];
#pragma unroll
        for (int i = 0; i < 4; ++i) {
            const float4* xp = (const float4*)(x + rows[nb * 4 + i] * Cc + cb * 8);
            *(float4*)&xs[i][0] = xp[0];
            *(float4*)&xs[i][4] = xp[1];
        }
#pragma unroll
        for (int k = 0; k < KSc; ++k) {
            const float4 q4 = *(const float4*)&qs[tA][k][nb * 4];
#pragma unroll
            for (int j = 0; j < 8; ++j) {
                float a = y[k][j];
                a = fmaf(q4.x, xs[0][j], a);
                a = fmaf(q4.y, xs[1][j], a);
                a = fmaf(q4.z, xs[2][j], a);
                a = fmaf(q4.w, xs[3][j], a);
                y[k][j] = a;
            }
        }
    }

    // ---- MFMA projection: res[16x32] = y[16x288] . W[288x32], bf16 hi/lo split ----
    floatx4 acc0 = {0.f, 0.f, 0.f, 0.f};
    floatx4 acc1 = {0.f, 0.f, 0.f, 0.f};
#pragma unroll
    for (int k = 0; k < KSc; ++k) {
        short8 ah, al;
#pragma unroll
        for (int j = 0; j < 8; ++j) {
            const unsigned int yb = __float_as_uint(y[k][j]);
            ah[j] = (short)(yb >> 16);
            const float hif = __uint_as_float(yb & 0xFFFF0000u);
            const float lof = y[k][j] - hif;
            al[j] = (short)(__float_as_uint(lof) >> 16);
        }
        // W fragments straight from global (hot in L1: 36.9 KB shared by all waves)
        const short8 bh0 = *(const short8*)(wf + ((k * 2 + 0) * 64 + l64) * 8);
        const short8 bh1 = *(const short8*)(wf + ((k * 2 + 1) * 64 + l64) * 8);
        const short8 bl0 = *(const short8*)(wf + WFE + ((k * 2 + 0) * 64 + l64) * 8);
        const short8 bl1 = *(const short8*)(wf + WFE + ((k * 2 + 1) * 64 + l64) * 8);
        acc0 = __builtin_amdgcn_mfma_f32_16x16x32_bf16(ah, bh0, acc0, 0, 0, 0);
        acc0 = __builtin_amdgcn_mfma_f32_16x16x32_bf16(al, bh0, acc0, 0, 0, 0);
        acc0 = __builtin_amdgcn_mfma_f32_16x16x32_bf16(ah, bl0, acc0, 0, 0, 0);
        acc1 = __builtin_amdgcn_mfma_f32_16x16x32_bf16(ah, bh1, acc1, 0, 0, 0);
        acc1 = __builtin_amdgcn_mfma_f32_16x16x32_bf16(al, bh1, acc1, 0, 0, 0);
        acc1 = __builtin_amdgcn_mfma_f32_16x16x32_bf16(ah, bl1, acc1, 0, 0, 0);
    }

    // ---- epilogue: D row = cb*4 + r (task), col = oo; inv via shfl; bias+relu ----
    const float b0 = bvec[oo], b1 = bvec[oo + 16];
#pragma unroll
    for (int r = 0; r < 4; ++r) {
        const int tl   = cb * 4 + r;
        const float nv = __shfl(inv_local, tl, 64);   // lane tl holds inv of task t0+tl
        const int tsk  = t0 + tl;
        out[tsk * OUTc + oo]      = fmaxf(fmaf(acc0[r], nv, b0), 0.f);
        out[tsk * OUTc + oo + 16] = fmaxf(fmaf(acc1[r], nv, b1), 0.f);
    }
}

extern "C" void kernel_launch(void* const* d_in, const int* in_sizes, int n_in,
                              void* d_out, int out_size, void* d_ws, size_t ws_size,
                              hipStream_t stream)
{
    const float* x    = (const float*)d_in[0];
    const float* W    = (const float*)d_in[1];
    const float* u    = (const float*)d_in[2];
    const float* cvec = (const float*)d_in[3];
    const float* bvec = (const float*)d_in[4];
    const int*   adj  = (const int*)d_in[5];
    float* out = (float*)d_out;

    float*          ux = (float*)d_ws;                                  // 1,920,000 B
    unsigned short* wf = (unsigned short*)((char*)d_ws + 1920000);      // 36,864 B

    prep_kernel<<<157 + 36, PBDIM, 0, stream>>>(x, u, W, ux, wf);
    fused_kernel<<<NITER, BDIM, 0, stream>>>(x, cvec, bvec, adj, ux, wf, out);
}

// Round 7
// 87.752 us; speedup vs baseline: 1.0972x; 1.0036x over previous
//
#include <hip/hip_runtime.h>
#include <math.h>

#define PBDIM 256   // prep kernel block
#define BDIM  64    // fused kernel: ONE wave per block

constexpr int Vc = 20000, Cc = 32, NBc = 12, KSc = 9, OUTc = 32;
constexpr int NTASK = 40000;
constexpr int MT    = 16;              // tasks per wave (MFMA M)
constexpr int NITER = NTASK / MT;      // 2500 exact = grid size
constexpr int UXH   = 16;              // halves per ux row (32 B, one cache line)
constexpr int XHS   = 32;              // halves per x_h row (64 B, one cache line)
constexpr int WFE   = KSc * 2 * 64 * 8;  // 9216 frag elems (hi); lo follows

typedef _Float16 half8 __attribute__((ext_vector_type(8)));  // 8 f16 = 4 VGPRs
typedef __attribute__((ext_vector_type(4))) float floatx4;   // MFMA C/D

// ---------- kernel 1: ux_h + x_h build (blocks 0..156) + W f16 frag build (157..192) ----------
__global__ __launch_bounds__(PBDIM)
void prep_kernel(const float* __restrict__ x, const float* __restrict__ u,
                 const float* __restrict__ W, _Float16* __restrict__ uxh,
                 _Float16* __restrict__ xh, _Float16* __restrict__ wf)
{
    if (blockIdx.x < 157) {
        __shared__ float us[Cc * KSc];
        for (int i = threadIdx.x; i < Cc * KSc; i += PBDIM) us[i] = u[i];
        __syncthreads();
        const int row = blockIdx.x * PBDIM + threadIdx.x;
        if (row >= NTASK) return;
        const float4* xr = (const float4*)(x + row * Cc);
        float4 xv[8];
#pragma unroll
        for (int i = 0; i < 8; ++i) xv[i] = xr[i];
        float acc[KSc];
#pragma unroll
        for (int k = 0; k < KSc; ++k) acc[k] = 0.f;
#pragma unroll
        for (int c = 0; c < Cc; ++c) {
            const float xc = ((const float*)xv)[c];
#pragma unroll
            for (int k = 0; k < KSc; ++k) acc[k] = fmaf(xc, us[c * KSc + k], acc[k]);
        }
        // ux row -> fp16, 32-B aligned (halves 0..8 used)
        half8 o;
#pragma unroll
        for (int k = 0; k < 8; ++k) o[k] = (_Float16)acc[k];
        *(half8*)(uxh + row * UXH) = o;
        uxh[row * UXH + 8] = (_Float16)acc[8];
        // x row -> fp16, 64-B aligned
#pragma unroll
        for (int q = 0; q < 4; ++q) {
            half8 hx;
#pragma unroll
            for (int j = 0; j < 8; ++j) hx[j] = (_Float16)((const float*)xv)[q * 8 + j];
            *(half8*)(xh + row * XHS + q * 8) = hx;
        }
    } else {
        // W f16 hi/lo MFMA B-fragments, B[c][o] layout for 16x16x32
        const int e = (blockIdx.x - 157) * PBDIM + threadIdx.x;   // [0, 9216)
        if (e >= WFE) return;
        const int j = e & 7;
        const int l = (e >> 3) & 63;
        const int h = (e >> 9) & 1;
        const int k = e >> 10;                  // 0..8
        const int c = (l >> 4) * 8 + j;         // B k-dim elem = channel
        const int o = (l & 15) + 16 * h;        // B n-dim = output col
        const float w = W[(c * KSc + k) * OUTc + o];
        const _Float16 wh = (_Float16)w;
        const _Float16 wl = (_Float16)(w - (float)wh);
        wf[e]       = wh;
        wf[WFE + e] = wl;
    }
}

// ---------- kernel 2: one wave = 16 tasks; softmax+aggregate+f16-MFMA, no barriers ----------
__global__ __launch_bounds__(BDIM, 3)
void fused_kernel(const float* __restrict__ cvec, const float* __restrict__ bvec,
                  const int* __restrict__ adj, const _Float16* __restrict__ uxh,
                  const _Float16* __restrict__ xh, const _Float16* __restrict__ wf,
                  float* __restrict__ out)
{
    __shared__ __align__(16) float qs[MT][KSc][NBc];   // 6912 B, only LDS use

    const int l64 = threadIdx.x;
    const int oo  = l64 & 15;     // MFMA n / D col
    const int cb  = l64 >> 4;     // c-block for A, row-quad for D
    const int t0  = blockIdx.x * MT;

    float ck[KSc];
#pragma unroll
    for (int k = 0; k < KSc; ++k) ck[k] = cvec[k];

    // ---- per-lane task metadata + HOISTED x_h gathers (rows depend only on adj) ----
    const int tA   = l64 & 15;                     // this lane's task (A row)
    const int task = t0 + tA;
    const int bb   = (task >= Vc) ? 1 : 0;
    const int v    = task - bb * Vc;
    int rows[NBc];
    float inv_local;
    {
        const int4* ar = (const int4*)(adj + v * NBc);   // 768 B/wave, L1-broadcast
        const int4 a0 = ar[0], a1 = ar[1], a2 = ar[2];
        int jv[NBc];
        jv[0] = a0.x; jv[1] = a0.y; jv[2]  = a0.z; jv[3]  = a0.w;
        jv[4] = a1.x; jv[5] = a1.y; jv[6]  = a1.z; jv[7]  = a1.w;
        jv[8] = a2.x; jv[9] = a2.y; jv[10] = a2.z; jv[11] = a2.w;
        int d = 0;
#pragma unroll
        for (int n = 0; n < NBc; ++n) {
            const bool pr = (jv[n] != 0);
            d += pr ? 1 : 0;
            rows[n] = pr ? (bb * Vc + jv[n] - 1) : 0;
        }
        inv_local = (d > 0) ? 1.f / (float)d : 0.f;
    }
    half8 xr[NBc];                                  // 12 rows x 8 halves: one 64-B line each
#pragma unroll
    for (int n = 0; n < NBc; ++n)
        xr[n] = *(const half8*)(xh + rows[n] * XHS + cb * 8);

    // ---- softmax: 3 passes x 64 lanes = 16 tasks x 12 neighbors ----
#pragma unroll
    for (int p = 0; p < 3; ++p) {
        const int unit = p * 64 + l64;              // [0,192)
        const int t    = (unit * 171) >> 11;        // floor(unit/12), exact for unit<192
        const int n    = unit - t * 12;
        const int tk   = t0 + t;
        const int bbp  = (tk >= Vc) ? 1 : 0;
        const int vp   = tk - bbp * Vc;
        const int jn   = adj[vp * NBc + n];         // coalesced (contiguous units)
        const bool pred = (jn != 0);
        const int row = pred ? (bbp * Vc + jn - 1) : 0;
        const half8 uo8 = *(const half8*)(uxh + tk * UXH);
        const _Float16 uoe = uxh[tk * UXH + 8];
        const half8 un8 = *(const half8*)(uxh + row * UXH);
        const _Float16 une = uxh[row * UXH + 8];
        float e[KSc];
        float mx = -3.0e38f;
#pragma unroll
        for (int k = 0; k < 8; ++k) {
            e[k] = (float)uo8[k] - (float)un8[k] + ck[k];
            mx = fmaxf(mx, e[k]);
        }
        e[8] = (float)uoe - (float)une + ck[8];
        mx = fmaxf(mx, e[8]);
        float s = 0.f;
#pragma unroll
        for (int k = 0; k < KSc; ++k) { e[k] = __expf(e[k] - mx); s += e[k]; }
        const float r = pred ? (1.f / s) : 0.f;     // q=0 for padded neighbors
#pragma unroll
        for (int k = 0; k < KSc; ++k) qs[t][k][n] = e[k] * r;
    }
    // same-wave LDS write->read below: DS ops issue in order, no barrier needed

    // ---- y phase in MFMA A-layout: lane holds y[k][j] for c = cb*8+j ----
    float y[KSc][8];
#pragma unroll
    for (int k = 0; k < KSc; ++k)
#pragma unroll
        for (int j = 0; j < 8; ++j) y[k][j] = 0.f;

#pragma unroll
    for (int nb = 0; nb < 3; ++nb) {
        float xs[4][8];
#pragma unroll
        for (int i = 0; i < 4; ++i)
#pragma unroll
            for (int j = 0; j < 8; ++j) xs[i][j] = (float)xr[nb * 4 + i][j];
#pragma unroll
        for (int k = 0; k < KSc; ++k) {
            const float4 q4 = *(const float4*)&qs[tA][k][nb * 4];
#pragma unroll
            for (int j = 0; j < 8; ++j) {
                float a = y[k][j];
                a = fmaf(q4.x, xs[0][j], a);
                a = fmaf(q4.y, xs[1][j], a);
                a = fmaf(q4.z, xs[2][j], a);
                a = fmaf(q4.w, xs[3][j], a);
                y[k][j] = a;
            }
        }
    }

    // ---- MFMA projection: res[16x32] = y[16x288] . W[288x32], f16 hi/lo split ----
    floatx4 acc0 = {0.f, 0.f, 0.f, 0.f};
    floatx4 acc1 = {0.f, 0.f, 0.f, 0.f};
#pragma unroll
    for (int k = 0; k < KSc; ++k) {
        half8 ah, al;
#pragma unroll
        for (int j = 0; j < 8; ++j) {
            const float yy = y[k][j];
            const _Float16 hh = (_Float16)yy;
            ah[j] = hh;
            al[j] = (_Float16)(yy - (float)hh);
        }
        // W fragments from global (36.9 KB shared by all waves, L1/L2-hot)
        const half8 bh0 = *(const half8*)(wf + ((k * 2 + 0) * 64 + l64) * 8);
        const half8 bh1 = *(const half8*)(wf + ((k * 2 + 1) * 64 + l64) * 8);
        const half8 bl0 = *(const half8*)(wf + WFE + ((k * 2 + 0) * 64 + l64) * 8);
        const half8 bl1 = *(const half8*)(wf + WFE + ((k * 2 + 1) * 64 + l64) * 8);
        acc0 = __builtin_amdgcn_mfma_f32_16x16x32_f16(ah, bh0, acc0, 0, 0, 0);
        acc0 = __builtin_amdgcn_mfma_f32_16x16x32_f16(al, bh0, acc0, 0, 0, 0);
        acc0 = __builtin_amdgcn_mfma_f32_16x16x32_f16(ah, bl0, acc0, 0, 0, 0);
        acc1 = __builtin_amdgcn_mfma_f32_16x16x32_f16(ah, bh1, acc1, 0, 0, 0);
        acc1 = __builtin_amdgcn_mfma_f32_16x16x32_f16(al, bh1, acc1, 0, 0, 0);
        acc1 = __builtin_amdgcn_mfma_f32_16x16x32_f16(ah, bl1, acc1, 0, 0, 0);
    }

    // ---- epilogue: D row = cb*4 + r (task), col = oo; inv via shfl; bias+relu ----
    const float b0 = bvec[oo], b1 = bvec[oo + 16];
#pragma unroll
    for (int r = 0; r < 4; ++r) {
        const int tl   = cb * 4 + r;
        const float nv = __shfl(inv_local, tl, 64);   // lane tl holds inv of task t0+tl
        const int tsk  = t0 + tl;
        out[tsk * OUTc + oo]      = fmaxf(fmaf(acc0[r], nv, b0), 0.f);
        out[tsk * OUTc + oo + 16] = fmaxf(fmaf(acc1[r], nv, b1), 0.f);
    }
}

extern "C" void kernel_launch(void* const* d_in, const int* in_sizes, int n_in,
                              void* d_out, int out_size, void* d_ws, size_t ws_size,
                              hipStream_t stream)
{
    const float* x    = (const float*)d_in[0];
    const float* W    = (const float*)d_in[1];
    const float* u    = (const float*)d_in[2];
    const float* cvec = (const float*)d_in[3];
    const float* bvec = (const float*)d_in[4];
    const int*   adj  = (const int*)d_in[5];
    float* out = (float*)d_out;

    _Float16* uxh = (_Float16*)d_ws;                              // 40000*16*2 = 1,280,000 B
    _Float16* xh  = (_Float16*)((char*)d_ws + 1280000);           // 40000*32*2 = 2,560,000 B
    _Float16* wf  = (_Float16*)((char*)d_ws + 1280000 + 2560000); // 2*9216*2   =    36,864 B

    prep_kernel<<<157 + 36, PBDIM, 0, stream>>>(x, u, W, uxh, xh, wf);
    fused_kernel<<<NITER, BDIM, 0, stream>>>(cvec, bvec, adj, uxh, xh, wf, out);
}

// Round 8
// 87.004 us; speedup vs baseline: 1.1066x; 1.0086x over previous
//
#include <hip/hip_runtime.h>
#include <math.h>

#define PBDIM 256   // prep kernel block
#define BDIM  64    // fused kernel: ONE wave per block

constexpr int Vc = 20000, Cc = 32, NBc = 12, KSc = 9, OUTc = 32;
constexpr int NTASK = 40000;
constexpr int MT    = 16;              // tasks per wave (MFMA M)
constexpr int NITER = NTASK / MT;      // 2500 exact = grid size
constexpr int UXH   = 16;              // halves per ux row (32 B, one cache line)
constexpr int XHS   = 32;              // halves per x_h row (64 B, one cache line)
constexpr int WFE   = KSc * 2 * 64 * 8;  // 9216 frag elems (hi); lo follows

typedef _Float16 half8 __attribute__((ext_vector_type(8)));  // 8 f16 = 4 VGPRs
typedef __attribute__((ext_vector_type(4))) float floatx4;   // MFMA C/D

// ---------- kernel 1: ux_h + x_h build (blocks 0..156) + W f16 frag build (157..192) ----------
__global__ __launch_bounds__(PBDIM)
void prep_kernel(const float* __restrict__ x, const float* __restrict__ u,
                 const float* __restrict__ W, _Float16* __restrict__ uxh,
                 _Float16* __restrict__ xh, _Float16* __restrict__ wf)
{
    if (blockIdx.x < 157) {
        __shared__ float us[Cc * KSc];
        for (int i = threadIdx.x; i < Cc * KSc; i += PBDIM) us[i] = u[i];
        __syncthreads();
        const int row = blockIdx.x * PBDIM + threadIdx.x;
        if (row >= NTASK) return;
        const float4* xr = (const float4*)(x + row * Cc);
        float4 xv[8];
#pragma unroll
        for (int i = 0; i < 8; ++i) xv[i] = xr[i];
        float acc[KSc];
#pragma unroll
        for (int k = 0; k < KSc; ++k) acc[k] = 0.f;
#pragma unroll
        for (int c = 0; c < Cc; ++c) {
            const float xc = ((const float*)xv)[c];
#pragma unroll
            for (int k = 0; k < KSc; ++k) acc[k] = fmaf(xc, us[c * KSc + k], acc[k]);
        }
        // ux row -> fp16, 32-B aligned (halves 0..8 used)
        half8 o;
#pragma unroll
        for (int k = 0; k < 8; ++k) o[k] = (_Float16)acc[k];
        *(half8*)(uxh + row * UXH) = o;
        uxh[row * UXH + 8] = (_Float16)acc[8];
        // x row -> fp16, 64-B aligned
#pragma unroll
        for (int q = 0; q < 4; ++q) {
            half8 hx;
#pragma unroll
            for (int j = 0; j < 8; ++j) hx[j] = (_Float16)((const float*)xv)[q * 8 + j];
            *(half8*)(xh + row * XHS + q * 8) = hx;
        }
    } else {
        // W f16 hi/lo MFMA B-fragments, B[c][o] layout for 16x16x32
        const int e = (blockIdx.x - 157) * PBDIM + threadIdx.x;   // [0, 9216)
        if (e >= WFE) return;
        const int j = e & 7;
        const int l = (e >> 3) & 63;
        const int h = (e >> 9) & 1;
        const int k = e >> 10;                  // 0..8
        const int c = (l >> 4) * 8 + j;         // B k-dim elem = channel
        const int o = (l & 15) + 16 * h;        // B n-dim = output col
        const float w = W[(c * KSc + k) * OUTc + o];
        const _Float16 wh = (_Float16)w;
        const _Float16 wl = (_Float16)(w - (float)wh);
        wf[e]       = wh;
        wf[WFE + e] = wl;
    }
}

// ---------- kernel 2: one wave = 16 tasks; register-dieted (no spill) ----------
__global__ __launch_bounds__(BDIM, 3)
void fused_kernel(const float* __restrict__ cvec, const float* __restrict__ bvec,
                  const int* __restrict__ adj, const _Float16* __restrict__ uxh,
                  const _Float16* __restrict__ xh, const _Float16* __restrict__ wf,
                  float* __restrict__ out)
{
    __shared__ __align__(16) float qs[MT][KSc][NBc];   // 6912 B, only LDS use

    const int l64 = threadIdx.x;
    const int oo  = l64 & 15;     // MFMA n / D col
    const int cb  = l64 >> 4;     // c-block for A, row-quad for D
    const int t0  = blockIdx.x * MT;

    float ck[KSc];
#pragma unroll
    for (int k = 0; k < KSc; ++k) ck[k] = cvec[k];

    // ---- per-lane task metadata; gather x rows; convert to fp32 IMMEDIATELY so
    //      rows[]/half-regs die before softmax (register diet: peak live ~150) ----
    const int tA   = l64 & 15;                     // this lane's task (A row)
    const int task = t0 + tA;
    const int bb   = (task >= Vc) ? 1 : 0;
    const int v    = task - bb * Vc;
    float inv_local;
    float xs[NBc][8];                              // 96 VGPR: the big resident array
    {
        const int4* ar = (const int4*)(adj + v * NBc);   // 768 B/wave, L1-broadcast
        const int4 a0 = ar[0], a1 = ar[1], a2 = ar[2];
        int jv[NBc];
        jv[0] = a0.x; jv[1] = a0.y; jv[2]  = a0.z; jv[3]  = a0.w;
        jv[4] = a1.x; jv[5] = a1.y; jv[6]  = a1.z; jv[7]  = a1.w;
        jv[8] = a2.x; jv[9] = a2.y; jv[10] = a2.z; jv[11] = a2.w;
        int d = 0;
        int rows[NBc];
#pragma unroll
        for (int n = 0; n < NBc; ++n) {
            const bool pr = (jv[n] != 0);
            d += pr ? 1 : 0;
            rows[n] = pr ? (bb * Vc + jv[n] - 1) : 0;
        }
        inv_local = (d > 0) ? 1.f / (float)d : 0.f;
        half8 xr[NBc];                              // transient: dead after convert
#pragma unroll
        for (int n = 0; n < NBc; ++n)
            xr[n] = *(const half8*)(xh + rows[n] * XHS + cb * 8);
#pragma unroll
        for (int n = 0; n < NBc; ++n)
#pragma unroll
            for (int j = 0; j < 8; ++j) xs[n][j] = (float)xr[n][j];
    }

    // ---- softmax: 3 passes x 64 lanes = 16 tasks x 12 neighbors (r7-identical) ----
#pragma unroll
    for (int p = 0; p < 3; ++p) {
        const int unit = p * 64 + l64;              // [0,192)
        const int t    = (unit * 171) >> 11;        // floor(unit/12), exact for unit<192
        const int n    = unit - t * 12;
        const int tk   = t0 + t;
        const int bbp  = (tk >= Vc) ? 1 : 0;
        const int vp   = tk - bbp * Vc;
        const int jn   = adj[vp * NBc + n];         // coalesced (contiguous units)
        const bool pred = (jn != 0);
        const int row = pred ? (bbp * Vc + jn - 1) : 0;
        const half8 uo8 = *(const half8*)(uxh + tk * UXH);
        const _Float16 uoe = uxh[tk * UXH + 8];
        const half8 un8 = *(const half8*)(uxh + row * UXH);
        const _Float16 une = uxh[row * UXH + 8];
        float e[KSc];
        float mx = -3.0e38f;
#pragma unroll
        for (int k = 0; k < 8; ++k) {
            e[k] = (float)uo8[k] - (float)un8[k] + ck[k];
            mx = fmaxf(mx, e[k]);
        }
        e[8] = (float)uoe - (float)une + ck[8];
        mx = fmaxf(mx, e[8]);
        float s = 0.f;
#pragma unroll
        for (int k = 0; k < KSc; ++k) { e[k] = __expf(e[k] - mx); s += e[k]; }
        const float r = pred ? (1.f / s) : 0.f;     // q=0 for padded neighbors
#pragma unroll
        for (int k = 0; k < KSc; ++k) qs[t][k][n] = e[k] * r;
    }
    // same-wave LDS write->read below: DS ops issue in order, no barrier needed

    // ---- fused y+pack+MFMA k-loop: y[9][8] never materialized (was 72 spilled regs) ----
    floatx4 acc0 = {0.f, 0.f, 0.f, 0.f};
    floatx4 acc1 = {0.f, 0.f, 0.f, 0.f};
#pragma unroll
    for (int k = 0; k < KSc; ++k) {
        const float4 qa = *(const float4*)&qs[tA][k][0];
        const float4 qb = *(const float4*)&qs[tA][k][4];
        const float4 qc = *(const float4*)&qs[tA][k][8];
        float y8[8];
#pragma unroll
        for (int j = 0; j < 8; ++j) {               // n = 0..11 sequential: bitwise-identical to r7
            float a = 0.f;
            a = fmaf(qa.x, xs[0][j], a);  a = fmaf(qa.y, xs[1][j], a);
            a = fmaf(qa.z, xs[2][j], a);  a = fmaf(qa.w, xs[3][j], a);
            a = fmaf(qb.x, xs[4][j], a);  a = fmaf(qb.y, xs[5][j], a);
            a = fmaf(qb.z, xs[6][j], a);  a = fmaf(qb.w, xs[7][j], a);
            a = fmaf(qc.x, xs[8][j], a);  a = fmaf(qc.y, xs[9][j], a);
            a = fmaf(qc.z, xs[10][j], a); a = fmaf(qc.w, xs[11][j], a);
            y8[j] = a;
        }
        half8 ah, al;
#pragma unroll
        for (int j = 0; j < 8; ++j) {
            const _Float16 hh = (_Float16)y8[j];
            ah[j] = hh;
            al[j] = (_Float16)(y8[j] - (float)hh);
        }
        const half8 bh0 = *(const half8*)(wf + ((k * 2 + 0) * 64 + l64) * 8);
        const half8 bh1 = *(const half8*)(wf + ((k * 2 + 1) * 64 + l64) * 8);
        const half8 bl0 = *(const half8*)(wf + WFE + ((k * 2 + 0) * 64 + l64) * 8);
        const half8 bl1 = *(const half8*)(wf + WFE + ((k * 2 + 1) * 64 + l64) * 8);
        acc0 = __builtin_amdgcn_mfma_f32_16x16x32_f16(ah, bh0, acc0, 0, 0, 0);
        acc0 = __builtin_amdgcn_mfma_f32_16x16x32_f16(al, bh0, acc0, 0, 0, 0);
        acc0 = __builtin_amdgcn_mfma_f32_16x16x32_f16(ah, bl0, acc0, 0, 0, 0);
        acc1 = __builtin_amdgcn_mfma_f32_16x16x32_f16(ah, bh1, acc1, 0, 0, 0);
        acc1 = __builtin_amdgcn_mfma_f32_16x16x32_f16(al, bh1, acc1, 0, 0, 0);
        acc1 = __builtin_amdgcn_mfma_f32_16x16x32_f16(ah, bl1, acc1, 0, 0, 0);
    }

    // ---- epilogue: D row = cb*4 + r (task), col = oo; inv via shfl; bias+relu ----
    const float b0 = bvec[oo], b1 = bvec[oo + 16];
#pragma unroll
    for (int r = 0; r < 4; ++r) {
        const int tl   = cb * 4 + r;
        const float nv = __shfl(inv_local, tl, 64);   // lane tl holds inv of task t0+tl
        const int tsk  = t0 + tl;
        out[tsk * OUTc + oo]      = fmaxf(fmaf(acc0[r], nv, b0), 0.f);
        out[tsk * OUTc + oo + 16] = fmaxf(fmaf(acc1[r], nv, b1), 0.f);
    }
}

extern "C" void kernel_launch(void* const* d_in, const int* in_sizes, int n_in,
                              void* d_out, int out_size, void* d_ws, size_t ws_size,
                              hipStream_t stream)
{
    const float* x    = (const float*)d_in[0];
    const float* W    = (const float*)d_in[1];
    const float* u    = (const float*)d_in[2];
    const float* cvec = (const float*)d_in[3];
    const float* bvec = (const float*)d_in[4];
    const int*   adj  = (const int*)d_in[5];
    float* out = (float*)d_out;

    _Float16* uxh = (_Float16*)d_ws;                              // 40000*16*2 = 1,280,000 B
    _Float16* xh  = (_Float16*)((char*)d_ws + 1280000);           // 40000*32*2 = 2,560,000 B
    _Float16* wf  = (_Float16*)((char*)d_ws + 1280000 + 2560000); // 2*9216*2   =    36,864 B

    prep_kernel<<<157 + 36, PBDIM, 0, stream>>>(x, u, W, uxh, xh, wf);
    fused_kernel<<<NITER, BDIM, 0, stream>>>(cvec, bvec, adj, uxh, xh, wf, out);
}